// Round 4
// baseline (166.313 us; speedup 1.0000x reference)
//
#include <hip/hip_runtime.h>
#include <hip/hip_bf16.h>

#define B_N 8192
#define D_K 256
#define BM  64
#define BN  128
#define JSPLIT 4
#define JSPAN (B_N / JSPLIT)     // 2048
#define NTILE (JSPAN / BN)       // 16
#define NCLS 1024
#define INVT 14.285714285714286f
#define C1   20.60992907f        // INVT * log2(e)

typedef __bf16 bf16x8 __attribute__((ext_vector_type(8)));
typedef float  f32x16 __attribute__((ext_vector_type(16)));
typedef float  f32x4  __attribute__((ext_vector_type(4)));

#define AS1 __attribute__((address_space(1)))
#define AS3 __attribute__((address_space(3)))

__device__ __forceinline__ unsigned short f32_to_bf16_rne(float f) {
    unsigned int u = __float_as_uint(f);
    unsigned int r = (u + 0x7FFFu + ((u >> 16) & 1u)) >> 16;
    return (unsigned short)r;
}
__device__ __forceinline__ float bf16_to_f32(unsigned short u) {
    return __uint_as_float(((unsigned int)u) << 16);
}

// grid 1024 x 256: zero C (1024x256 fp32), hist, out
__global__ void zero_kernel(float* __restrict__ out, int* __restrict__ hist,
                            float* __restrict__ Cmat) {
    int g = blockIdx.x * 256 + threadIdx.x;
    Cmat[g] = 0.0f;
    if (g < NCLS) hist[g] = 0;
    if (g == 0) out[0] = 0.0f;
}

// grid 2048 x 256: one wave per row. float4 loads, shfl reduce, bf16 store,
// centroid atomics (fp32) + label histogram.
__global__ void norm_kernel(const float* __restrict__ emb,
                            const int* __restrict__ labels,
                            unsigned short* __restrict__ en,
                            float* __restrict__ Cmat,
                            int* __restrict__ hist) {
    const int t = threadIdx.x;
    const int w = t >> 6, l = t & 63;
    const int row = blockIdx.x * 4 + w;
    f32x4 x = *reinterpret_cast<const f32x4*>(emb + (size_t)row * D_K + l * 4);
    float ss = x[0]*x[0] + x[1]*x[1] + x[2]*x[2] + x[3]*x[3];
    #pragma unroll
    for (int m = 1; m < 64; m <<= 1) ss += __shfl_xor(ss, m, 64);
    float sc = 1.0f / fmaxf(sqrtf(ss), 1e-12f);
    const int lab = labels[row];
    float xn[4];
    ushort4 o;
    #pragma unroll
    for (int k = 0; k < 4; ++k) xn[k] = x[k] * sc;
    o.x = f32_to_bf16_rne(xn[0]); o.y = f32_to_bf16_rne(xn[1]);
    o.z = f32_to_bf16_rne(xn[2]); o.w = f32_to_bf16_rne(xn[3]);
    *reinterpret_cast<ushort4*>(en + (size_t)row * D_K + l * 4) = o;
    #pragma unroll
    for (int k = 0; k < 4; ++k)
        atomicAdd(&Cmat[lab * D_K + l * 4 + k], xn[k]);
    if (l == 0) atomicAdd(&hist[lab], 1);
}

// BM=64 i-rows/block (split: wave w -> i-half w>>1, j-half w&1), BN=128 j-tile
// staged to LDS (XOR-swizzled), JSPLIT=4 -> grid 512 = 2 blocks/CU.
// Inner loop is pure softmax-denominator: s += exp2(fma(dot,C1,-C1)).
__launch_bounds__(256, 2)
__global__ void loss_kernel(const unsigned short* __restrict__ en,
                            float* __restrict__ s_part) {
    __shared__ __align__(16) unsigned short Bls[BN * D_K];   // 64 KB
    __shared__ float comb[4][32];

    const int t  = threadIdx.x;
    const int l  = t & 63;
    const int w  = t >> 6;
    const int ir = l & 31;
    const int h  = l >> 5;
    const int jh = w & 1;
    const int ih = w >> 1;

    // XCD swizzle: each XCD owns one jsplit-span (1MB, L2-resident) and a
    // contiguous itile range.
    const int b      = blockIdx.x;
    const int swz    = (b & 7) * 64 + (b >> 3);
    const int jsplit = swz >> 7;
    const int itile  = swz & 127;
    const int ibase  = itile * BM;

    // resident i-side fragments: 16 ks-slices, 64 VGPR
    bf16x8 bi[16];
    {
        const unsigned short* ap =
            en + (size_t)(ibase + ih * 32 + ir) * D_K + h * 8;
        #pragma unroll
        for (int ks = 0; ks < 16; ++ks)
            bi[ks] = *reinterpret_cast<const bf16x8*>(ap + ks * 16);
    }

    // hoisted staging addresses: srcm is tile-invariant
    const int srcm = (t & 31) ^ ((t >> 5) & 7);
    const unsigned short* gb = en + (size_t)(jsplit * JSPAN) * D_K
                                  + (size_t)(t >> 5) * D_K + srcm * 8;
    char* lds_base = (char*)Bls + t * 16;
    const char* abase = (const char*)Bls + (size_t)(jh * 64 + ir) * 512;
    const int xr = (ir & 7) << 4;

    float s_acc = 0.0f;

    for (int it = 0; it < NTILE; ++it) {
        __syncthreads();
        #pragma unroll
        for (int rd = 0; rd < 16; ++rd) {
            __builtin_amdgcn_global_load_lds(
                (const AS1 void*)(gb + rd * (8 * D_K)),
                (AS3 void*)(lds_base + rd * 4096), 16, 0, 0);
        }
        gb += (size_t)BN * D_K;
        __syncthreads();

        #pragma unroll
        for (int jg2 = 0; jg2 < 2; ++jg2) {
            f32x16 acc;
            #pragma unroll
            for (int q = 0; q < 16; ++q) acc[q] = 0.0f;
            const char* arow = abase + jg2 * (32 * 512);
            #pragma unroll
            for (int ks = 0; ks < 16; ++ks) {
                const bf16x8 af = *reinterpret_cast<const bf16x8*>(
                    arow + ((((ks << 1) | h) << 4) ^ xr));
                acc = __builtin_amdgcn_mfma_f32_32x32x16_bf16(af, bi[ks], acc,
                                                              0, 0, 0);
            }
            #pragma unroll
            for (int q = 0; q < 16; ++q)
                s_acc += exp2f(fmaf(acc[q], C1, -C1));
        }
    }

    s_acc += __shfl_xor(s_acc, 32, 64);
    if (h == 0) comb[w][ir] = s_acc;
    __syncthreads();
    if (t < BM) {
        float sv = comb[(t >> 5) * 2][t & 31] + comb[(t >> 5) * 2 + 1][t & 31];
        s_part[jsplit * B_N + ibase + t] = sv;
    }
}

// grid 2048 x 256: one wave per row i. loss_i = lse_i - ps_i/pc_i with
// ps from centroid trick: (en_i . C[lab_i] - en_i . en_i) * INVT.
__global__ void final_kernel(const unsigned short* __restrict__ en,
                             const int* __restrict__ labels,
                             const float* __restrict__ s_part,
                             const float* __restrict__ Cmat,
                             const int* __restrict__ hist,
                             float* __restrict__ out) {
    const int t = threadIdx.x, w = t >> 6, l = t & 63;
    const int i = blockIdx.x * 4 + w;
    const int lab = labels[i];
    ushort4 eu = *reinterpret_cast<const ushort4*>(en + (size_t)i * D_K + l * 4);
    f32x4  c4  = *reinterpret_cast<const f32x4*>(Cmat + lab * D_K + l * 4);
    float e0 = bf16_to_f32(eu.x), e1 = bf16_to_f32(eu.y),
          e2 = bf16_to_f32(eu.z), e3 = bf16_to_f32(eu.w);
    float dot  = e0 * c4[0] + e1 * c4[1] + e2 * c4[2] + e3 * c4[3];
    float self = e0 * e0 + e1 * e1 + e2 * e2 + e3 * e3;
    #pragma unroll
    for (int m = 1; m < 64; m <<= 1) {
        dot  += __shfl_xor(dot, m, 64);
        self += __shfl_xor(self, m, 64);
    }
    __shared__ float part[4];
    if (l == 0) {
        float s = s_part[i] + s_part[B_N + i] + s_part[2 * B_N + i]
                + s_part[3 * B_N + i];
        int pc = hist[lab] - 1;
        float lse  = INVT + logf(s);
        float ps   = (dot - self) * INVT;
        float loss = (pc > 0) ? (lse - ps / (float)pc) : 0.0f;
        part[w] = loss;
    }
    __syncthreads();
    if (t == 0)
        atomicAdd(out, (part[0] + part[1] + part[2] + part[3]) * (1.0f / B_N));
}

extern "C" void kernel_launch(void* const* d_in, const int* in_sizes, int n_in,
                              void* d_out, int out_size, void* d_ws, size_t ws_size,
                              hipStream_t stream) {
    const float* emb    = (const float*)d_in[0];
    const int*   labels = (const int*)d_in[1];
    float*       out    = (float*)d_out;

    unsigned short* en = (unsigned short*)d_ws;                    // 4 MB
    float* s_part = (float*)((char*)d_ws + (size_t)B_N * D_K * 2); // 128 KB
    int*   hist   = (int*)(s_part + JSPLIT * B_N);                 // 4 KB
    float* Cmat   = (float*)(hist + NCLS);                         // 1 MB

    hipLaunchKernelGGL(zero_kernel, dim3(NCLS * D_K / 256), dim3(256), 0,
                       stream, out, hist, Cmat);
    hipLaunchKernelGGL(norm_kernel, dim3(B_N / 4), dim3(256), 0, stream,
                       emb, labels, en, Cmat, hist);
    hipLaunchKernelGGL(loss_kernel, dim3(128 * JSPLIT), dim3(256), 0, stream,
                       en, s_part);
    hipLaunchKernelGGL(final_kernel, dim3(B_N / 4), dim3(256), 0, stream,
                       en, labels, s_part, Cmat, hist, out);
}

// Round 5
// 135.863 us; speedup vs baseline: 1.2241x; 1.2241x over previous
//
#include <hip/hip_runtime.h>
#include <hip/hip_bf16.h>

#define B_N 8192
#define D_K 256
#define BM  64
#define BN  64
#define JSPLIT 4
#define JSPAN (B_N / JSPLIT)     // 2048
#define NTILE (JSPAN / BN)       // 32
#define NCLS 1024
#define INVT 14.285714285714286f
#define C1   20.60992907f        // INVT * log2(e)

typedef __bf16 bf16x8 __attribute__((ext_vector_type(8)));
typedef float  f32x16 __attribute__((ext_vector_type(16)));
typedef float  f32x4  __attribute__((ext_vector_type(4)));

#define AS1 __attribute__((address_space(1)))
#define AS3 __attribute__((address_space(3)))

__device__ __forceinline__ unsigned short f32_to_bf16_rne(float f) {
    unsigned int u = __float_as_uint(f);
    unsigned int r = (u + 0x7FFFu + ((u >> 16) & 1u)) >> 16;
    return (unsigned short)r;
}
__device__ __forceinline__ float bf16_to_f32(unsigned short u) {
    return __uint_as_float(((unsigned int)u) << 16);
}

__global__ void zero_kernel(float* __restrict__ out, int* __restrict__ hist) {
    int g = blockIdx.x * 256 + threadIdx.x;
    if (g < NCLS) hist[g] = 0;
    if (g == 0) out[0] = 0.0f;
}

// grid 2048 x 256: one wave per row. float4 loads, shfl reduce, bf16 store,
// label histogram (8192 int atomics total — measured cheap).
__global__ void norm_kernel(const float* __restrict__ emb,
                            const int* __restrict__ labels,
                            unsigned short* __restrict__ en,
                            int* __restrict__ hist) {
    const int t = threadIdx.x;
    const int w = t >> 6, l = t & 63;
    const int row = blockIdx.x * 4 + w;
    f32x4 x = *reinterpret_cast<const f32x4*>(emb + (size_t)row * D_K + l * 4);
    float ss = x[0]*x[0] + x[1]*x[1] + x[2]*x[2] + x[3]*x[3];
    #pragma unroll
    for (int m = 1; m < 64; m <<= 1) ss += __shfl_xor(ss, m, 64);
    float sc = 1.0f / fmaxf(sqrtf(ss), 1e-12f);
    ushort4 o;
    o.x = f32_to_bf16_rne(x[0] * sc); o.y = f32_to_bf16_rne(x[1] * sc);
    o.z = f32_to_bf16_rne(x[2] * sc); o.w = f32_to_bf16_rne(x[3] * sc);
    *reinterpret_cast<ushort4*>(en + (size_t)row * D_K + l * 4) = o;
    if (l == 0) atomicAdd(&hist[labels[row]], 1);
}

// BM=64 i-rows/block (wave w: i-half w>>1, j-half w&1), BN=64 j-tiles,
// double-buffered LDS with 2-phase pipeline: stage(next) issued BEFORE
// compute(cur), one vmcnt(0)+barrier per tile. JSPLIT=4 -> grid 512 = 2/CU.
// ps includes the self term (subtracted in final_kernel) -> no diag branch.
__launch_bounds__(256, 2)
__global__ void loss_kernel(const unsigned short* __restrict__ en,
                            const int* __restrict__ labels,
                            float* __restrict__ s_part,
                            float* __restrict__ ps_part) {
    __shared__ __align__(16) unsigned short Bls[2][BN * D_K];  // 2 x 32 KB
    __shared__ __align__(16) int Lab_s[JSPAN];                 // 8 KB
    __shared__ float comb[2][4][32];

    const int t  = threadIdx.x;
    const int l  = t & 63;
    const int w  = t >> 6;
    const int ir = l & 31;
    const int h  = l >> 5;
    const int jh = w & 1;
    const int ih = w >> 1;

    // XCD swizzle: 2 XCDs per jsplit-span (1 MB j-panel, L2-resident).
    const int b      = blockIdx.x;
    const int swz    = (b & 7) * 64 + (b >> 3);
    const int jsplit = swz >> 7;
    const int itile  = swz & 127;
    const int ibase  = itile * BM;
    const int j0     = jsplit * JSPAN;

    // resident i-side fragments (B operand): 16 ks-slices, 64 VGPR
    bf16x8 bi[16];
    {
        const unsigned short* ap =
            en + (size_t)(ibase + ih * 32 + ir) * D_K + h * 8;
        #pragma unroll
        for (int ks = 0; ks < 16; ++ks)
            bi[ks] = *reinterpret_cast<const bf16x8*>(ap + ks * 16);
    }
    const int li = labels[ibase + ih * 32 + (l & 31)];

    // hoisted staging addresses (srcm tile- and rd-invariant: rd*8 % 8 == 0)
    const int srcm = (t & 31) ^ ((t >> 5) & 7);
    const unsigned short* gb =
        en + (size_t)(j0 + (t >> 5)) * D_K + srcm * 8;
    const char* abase0 = (const char*)Bls[0] + (size_t)(jh * 32 + ir) * 512;
    const char* abase1 = (const char*)Bls[1] + (size_t)(jh * 32 + ir) * 512;
    const int xr = (ir & 7) << 4;

    float s0 = 0.f, s1 = 0.f, ps0 = 0.f, ps1 = 0.f;

#define STAGE(bufp, itv)                                                     \
    {                                                                        \
        const unsigned short* gsrc = gb + (size_t)(itv) * (BN * D_K);        \
        char* ldst = (char*)(bufp) + t * 16;                                 \
        _Pragma("unroll")                                                    \
        for (int rd = 0; rd < 8; ++rd)                                       \
            __builtin_amdgcn_global_load_lds(                                \
                (const AS1 void*)(gsrc + rd * 2048),                         \
                (AS3 void*)(ldst + rd * 4096), 16, 0, 0);                    \
    }

#define TILE_COMPUTE(arow_b, itv)                                            \
    {                                                                        \
        int ljv[16];                                                         \
        {                                                                    \
            const int lb = (itv) * BN + jh * 32 + h * 4;                     \
            *(int4*)&ljv[0]  = *(const int4*)&Lab_s[lb];                     \
            *(int4*)&ljv[4]  = *(const int4*)&Lab_s[lb + 8];                 \
            *(int4*)&ljv[8]  = *(const int4*)&Lab_s[lb + 16];                \
            *(int4*)&ljv[12] = *(const int4*)&Lab_s[lb + 24];                \
        }                                                                    \
        f32x16 acc;                                                          \
        _Pragma("unroll")                                                    \
        for (int q = 0; q < 16; ++q) acc[q] = 0.0f;                          \
        _Pragma("unroll")                                                    \
        for (int ks = 0; ks < 16; ++ks) {                                    \
            const bf16x8 af = *reinterpret_cast<const bf16x8*>(              \
                (arow_b) + ((((ks << 1) | h) << 4) ^ xr));                   \
            acc = __builtin_amdgcn_mfma_f32_32x32x16_bf16(af, bi[ks], acc,   \
                                                          0, 0, 0);          \
        }                                                                    \
        _Pragma("unroll")                                                    \
        for (int q = 0; q < 16; ++q) {                                       \
            float dot = acc[q];                                              \
            float e = __builtin_amdgcn_exp2f(fmaf(dot, C1, -C1));            \
            if (q & 1) { s1 += e; ps1 += (ljv[q] == li) ? dot : 0.0f; }      \
            else       { s0 += e; ps0 += (ljv[q] == li) ? dot : 0.0f; }      \
        }                                                                    \
    }

    // prologue: stage tile 0 + all j-labels of this span
    STAGE(Bls[0], 0);
    #pragma unroll
    for (int k = 0; k < 8; ++k)
        Lab_s[t + k * 256] = labels[j0 + t + k * 256];
    __syncthreads();

    for (int it = 0; it < NTILE; it += 2) {
        if (it + 1 < NTILE) STAGE(Bls[1], it + 1);
        TILE_COMPUTE(abase0, it);
        asm volatile("s_waitcnt vmcnt(0)");
        __syncthreads();
        if (it + 2 < NTILE) STAGE(Bls[0], it + 2);
        TILE_COMPUTE(abase1, it + 1);
        asm volatile("s_waitcnt vmcnt(0)");
        __syncthreads();
    }
#undef STAGE
#undef TILE_COMPUTE

    float s_acc  = s0 + s1;
    float ps_acc = ps0 + ps1;
    s_acc  += __shfl_xor(s_acc, 32, 64);
    ps_acc += __shfl_xor(ps_acc, 32, 64);
    if (h == 0) { comb[0][w][ir] = s_acc; comb[1][w][ir] = ps_acc; }
    __syncthreads();
    if (t < BM) {
        const int q0 = (t >> 5) * 2, q1 = q0 + 1, r = t & 31;
        s_part[jsplit * B_N + ibase + t]  = comb[0][q0][r] + comb[0][q1][r];
        ps_part[jsplit * B_N + ibase + t] = comb[1][q0][r] + comb[1][q1][r];
    }
}

// grid 2048 x 256: wave per row. self = sum(en_i^2) recomputed (subtracts the
// diagonal term from ps); loss from per-row partials; single atomic per block.
__global__ void final_kernel(const unsigned short* __restrict__ en,
                             const int* __restrict__ labels,
                             const float* __restrict__ s_part,
                             const float* __restrict__ ps_part,
                             const int* __restrict__ hist,
                             float* __restrict__ out) {
    const int t = threadIdx.x, w = t >> 6, l = t & 63;
    const int i = blockIdx.x * 4 + w;
    ushort4 eu = *reinterpret_cast<const ushort4*>(en + (size_t)i * D_K + l * 4);
    float e0 = bf16_to_f32(eu.x), e1 = bf16_to_f32(eu.y),
          e2 = bf16_to_f32(eu.z), e3 = bf16_to_f32(eu.w);
    float self = e0 * e0 + e1 * e1 + e2 * e2 + e3 * e3;
    #pragma unroll
    for (int m = 1; m < 64; m <<= 1) self += __shfl_xor(self, m, 64);
    __shared__ float part[4];
    if (l == 0) {
        float s  = s_part[i] + s_part[B_N + i] + s_part[2 * B_N + i]
                 + s_part[3 * B_N + i];
        float ps = ps_part[i] + ps_part[B_N + i] + ps_part[2 * B_N + i]
                 + ps_part[3 * B_N + i] - self;
        int pc = hist[labels[i]] - 1;
        float loss = (pc > 0) ? (INVT + logf(s)) - ps * INVT / (float)pc : 0.0f;
        part[w] = loss;
    }
    __syncthreads();
    if (t == 0)
        atomicAdd(out, (part[0] + part[1] + part[2] + part[3]) * (1.0f / B_N));
}

extern "C" void kernel_launch(void* const* d_in, const int* in_sizes, int n_in,
                              void* d_out, int out_size, void* d_ws, size_t ws_size,
                              hipStream_t stream) {
    const float* emb    = (const float*)d_in[0];
    const int*   labels = (const int*)d_in[1];
    float*       out    = (float*)d_out;

    unsigned short* en = (unsigned short*)d_ws;                     // 4 MB
    float* s_part  = (float*)((char*)d_ws + (size_t)B_N * D_K * 2); // 128 KB
    float* ps_part = s_part + JSPLIT * B_N;                         // 128 KB
    int*   hist    = (int*)(ps_part + JSPLIT * B_N);                // 4 KB

    hipLaunchKernelGGL(zero_kernel, dim3(4), dim3(256), 0, stream, out, hist);
    hipLaunchKernelGGL(norm_kernel, dim3(B_N / 4), dim3(256), 0, stream,
                       emb, labels, en, hist);
    hipLaunchKernelGGL(loss_kernel, dim3(128 * JSPLIT), dim3(256), 0, stream,
                       en, labels, s_part, ps_part);
    hipLaunchKernelGGL(final_kernel, dim3(B_N / 4), dim3(256), 0, stream,
                       en, labels, s_part, ps_part, hist, out);
}